// Round 6
// baseline (400.488 us; speedup 1.0000x reference)
//
#include <hip/hip_runtime.h>
#include <hip/hip_bf16.h>

// WOQ int4-asym (tinygemm) linear: out[64,8192] = x @ dequant(w).T
// dequant: (q - 8)*scale + zp, groups of 128 along K.
//
// R8: attack the ~2.4 TB/s weight-stream wall with MAXIMUM per-row burst
// length. R7 still read each weight row in 512B chunks (one group); DRAM
// efficiency ~38%. Here: 256 blocks (1/CU), BN=32 rows, FULL K per block,
// K-step 512 -> per step each wave streams 4 rows x 2KB fully linear
// (2 consecutive 1KB wave-instructions per row); every weight row is read
// strictly sequentially over the kernel. Per step a CU issues 64KB of
// weight loads before any wait -> the vmcnt drain IS the BW wait.
//   - w dequanted on stage into frag-ordered 32KB bf16 LDS dbuf
//     (read side lane-contiguous conflict-free; write conflicts ~300cy
//     vs 6240cy/step budget - irrelevant).
//   - x staged per step into 64KB frag-ordered LDS tile (R7 mapping).
//   - issue order x -> scales -> w: write_x waits vmcnt(16) (x oldest),
//     never draining the w stream (R5 lesson).
//   - full-K ownership: no atomics, no zero_out, no reduce kernel.
//     In-block cross-wave k-slice reduce reuses x LDS. One launch.
// LDS 128KB -> 1 block/CU, 8 waves (2/SIMD). launch_bounds(512,2).

#define OUT_F 8192
#define IN_F  8192
#define M_TOK 64
#define BN    32
#define KSTEP 512
#define NSTEP (IN_F / KSTEP)   // 16

typedef short short8 __attribute__((ext_vector_type(8)));
typedef float f32x4  __attribute__((ext_vector_type(4)));

// pack two fp32 -> packed bf16 pair (RNE, v_cvt_pk_bf16_f32)
__device__ __forceinline__ unsigned pk(float lo, float hi) {
    __hip_bfloat162 h = __float22bfloat162_rn(float2{lo, hi});
    unsigned r;
    __builtin_memcpy(&r, &h, sizeof(r));
    return r;
}

__global__ __launch_bounds__(512, 2)
void woq_gemm(const float* __restrict__ x,
              const int*   __restrict__ qw,
              const float* __restrict__ sz,
              float*       __restrict__ outp) {
    // w tiles: frag-ordered bf16, chunk = ks*2+nj (32 chunks x 64 lanes x 16B)
    //   lane l of chunk holds w[nj*16+(l&15)][ks*32+(l>>4)*8 .. +8]
    __shared__ int lds_w[2][8192];     // 2 x 32 KB
    // x tile: frag-ordered bf16, chunk = ks*4+mi (64 chunks x 64 lanes x 16B)
    //   lane l holds x[mi*16+(l&15)][ks*32+(l>>4)*8 .. +8]
    __shared__ int lds_x[16384];       // 64 KB (reused as reduce scratch)

    const int t    = threadIdx.x;
    const int lane = t & 63;
    const int wv   = t >> 6;           // 0..7
    const int nlo  = lane & 15;
    const int quad = lane >> 4;
    const int n0   = blockIdx.x * BN;

    int4   wq[8];      // 4 rows x 2KB: instr i -> row wv*4+(i>>1), half i&1
    float2 sc[8];      // matching scale/zp
    float4 xv[8][2];   // x stage: 8 slots x 32B f32

    auto load_x = [&](int kb) {        // issue FIRST (oldest on vmcnt)
#pragma unroll
        for (int j = 0; j < 8; ++j) {
            const int slot  = t + 512 * j;
            const int chunk = slot >> 6;
            const int l     = slot & 63;
            const int m     = ((chunk & 3) << 4) + (l & 15);
            const int kk    = ((chunk >> 2) << 5) + ((l >> 4) << 3);
            const float4* p = (const float4*)(x + (size_t)m * IN_F + kb * KSTEP + kk);
            xv[j][0] = p[0];
            xv[j][1] = p[1];
        }
    };
    auto load_s = [&](int kb) {
#pragma unroll
        for (int i = 0; i < 8; ++i) {
            const int r  = wv * 4 + (i >> 1);
            const int gg = kb * 4 + (i & 1) * 2 + (lane >> 5);
            sc[i] = *(const float2*)(sz + ((size_t)gg * OUT_F + n0 + r) * 2);
        }
    };
    auto load_w = [&](int kb) {        // issue LAST (youngest: stays in flight)
#pragma unroll
        for (int i = 0; i < 8; ++i) {
            const int r    = wv * 4 + (i >> 1);
            const int koff = (i & 1) * 256 + lane * 4;    // ints within step
            wq[i] = *(const int4*)(qw + (size_t)(n0 + r) * IN_F + kb * KSTEP + koff);
        }
    };
    auto write_x = [&]() {             // waits x only (vmcnt(16))
#pragma unroll
        for (int j = 0; j < 8; ++j) {
            const int slot = t + 512 * j;
            int4 v;
            v.x = (int)pk(xv[j][0].x, xv[j][0].y);
            v.y = (int)pk(xv[j][0].z, xv[j][0].w);
            v.z = (int)pk(xv[j][1].x, xv[j][1].y);
            v.w = (int)pk(xv[j][1].z, xv[j][1].w);
            *(int4*)&lds_x[slot * 4] = v;
        }
    };
    auto write_w = [&](int buf) {      // waits w (the BW drain)
        int* wb = lds_w[buf];
#pragma unroll
        for (int i = 0; i < 8; ++i) {
            const int r    = wv * 4 + (i >> 1);
            const int koff = (i & 1) * 256 + lane * 4;
            const float s = sc[i].x;
            const float c = fmaf(-8.f, sc[i].x, sc[i].y);
            int2 v;
            v.x = (int)pk(fmaf((float)wq[i].x, s, c), fmaf((float)wq[i].y, s, c));
            v.y = (int)pk(fmaf((float)wq[i].z, s, c), fmaf((float)wq[i].w, s, c));
            const int chunk = (koff >> 5) * 2 + (r >> 4);
            const int ll    = (r & 15) + ((koff >> 3) & 3) * 16;
            const int idx   = (chunk * 64 + ll) * 4 + ((koff & 4) >> 1);
            *(int2*)&wb[idx] = v;
        }
    };

    f32x4 acc[4][2];
#pragma unroll
    for (int mi = 0; mi < 4; ++mi)
#pragma unroll
        for (int nj = 0; nj < 2; ++nj)
            acc[mi][nj] = (f32x4){0.f, 0.f, 0.f, 0.f};

    // ---- prologue: stage step 0 ----
    load_x(0); load_s(0); load_w(0);
    write_x(); write_w(0);
    __syncthreads();

    for (int kb = 0; kb < NSTEP; ++kb) {
        // issue next step's loads over this step's compute + drain
        if (kb + 1 < NSTEP) { load_x(kb + 1); load_s(kb + 1); load_w(kb + 1); }

        // compute step kb: wave wv owns k-slices {2wv, 2wv+1}
        const int* wb = lds_w[kb & 1];
#pragma unroll
        for (int s2 = 0; s2 < 2; ++s2) {
            const int ks = wv * 2 + s2;
            short8 b0 = *(const short8*)&wb[((ks * 2 + 0) * 64 + lane) * 4];
            short8 b1 = *(const short8*)&wb[((ks * 2 + 1) * 64 + lane) * 4];
            short8 a[4];
#pragma unroll
            for (int mi = 0; mi < 4; ++mi)
                a[mi] = *(const short8*)&lds_x[((ks * 4 + mi) * 64 + lane) * 4];
#pragma unroll
            for (int mi = 0; mi < 4; ++mi) {
                acc[mi][0] = __builtin_amdgcn_mfma_f32_16x16x32_bf16(a[mi], b0, acc[mi][0], 0, 0, 0);
                acc[mi][1] = __builtin_amdgcn_mfma_f32_16x16x32_bf16(a[mi], b1, acc[mi][1], 0, 0, 0);
            }
        }
        __syncthreads();               // all waves done reading lds_x / lds_w[kb&1]

        if (kb + 1 < NSTEP) {
            write_x();                 // x is oldest on vmcnt: w keeps flying
            write_w((kb + 1) & 1);     // vmcnt drain == the HBM BW wait
            __syncthreads();
        }
    }

    // ---- epilogue: cross-wave k-slice reduce (reuse lds_x), direct store ----
    f32x4* red = (f32x4*)lds_x;
#pragma unroll
    for (int mi = 0; mi < 4; ++mi)
#pragma unroll
        for (int nj = 0; nj < 2; ++nj)
            red[(wv * 8 + mi * 2 + nj) * 64 + lane] = acc[mi][nj];
    __syncthreads();
    {
        const int fi = wv;             // this wave finalizes fragment fi
        const int mi = fi >> 1, nj = fi & 1;
        f32x4 s = red[(0 * 8 + fi) * 64 + lane];
#pragma unroll
        for (int w2 = 1; w2 < 8; ++w2)
            s += red[(w2 * 8 + fi) * 64 + lane];
        // C/D layout: col = lane&15 (n), row = quad*4 + r (m)
#pragma unroll
        for (int r = 0; r < 4; ++r)
            outp[(size_t)(mi * 16 + quad * 4 + r) * OUT_F + n0 + nj * 16 + nlo] = s[r];
    }
}

extern "C" void kernel_launch(void* const* d_in, const int* in_sizes, int n_in,
                              void* d_out, int out_size, void* d_ws, size_t ws_size,
                              hipStream_t stream) {
    const float* x  = (const float*)d_in[0];
    const int*   qw = (const int*)d_in[1];
    const float* sz = (const float*)d_in[2];
    woq_gemm<<<dim3(OUT_F / BN), 512, 0, stream>>>(x, qw, sz, (float*)d_out);
}